// Round 3
// baseline (351.689 us; speedup 1.0000x reference)
//
#include <hip/hip_runtime.h>
#include <stdint.h>

#define N_ 256
#define H_ 1024
#define BS_ 128

// ---------------- workspace layout (floats) ----------------
// sk   : [128][1024]        @ 0          1 - tk^2
// bar  : 3 ints (+pad)      @ 131072     grid-barrier counters (memset to 0)
// opart: [16][3][128][256]  @ 229376     layer2 k-split partials
// jpart: [16][2][128][256]  @ 1802240    J h-split partials
// tg   : [3][128][1024]     @ 1802240    tanh activations (ALIASES jpart:
//                                        consumed in P2, overwritten in P4)
#define WS_SK    0
#define WS_BAR   131072
#define WS_OPART 229376
#define WS_JPART 1802240
#define WS_FLOATS 2850816   // ~11.4 MB

#define GRID_ 512   // 2 blocks/CU guaranteed resident (LDS 65.6KB, VGPR<=256)

// Device-scope grid barrier: release fence + atomic arrive, spin on agent-
// scope load, acquire fence (invalidates L1/L2 per gfx950 memory model --
// required: jpart aliases tg, and XCD L2s are not cross-coherent).
__device__ __forceinline__ void grid_barrier(int* cnt) {
    __syncthreads();
    if (threadIdx.x == 0) {
        __threadfence();                 // release: drain + make writes visible
        atomicAdd(cnt, 1);               // device-scope by default
        while (__hip_atomic_load(cnt, __ATOMIC_RELAXED,
                                 __HIP_MEMORY_SCOPE_AGENT) < GRID_)
            __builtin_amdgcn_s_sleep(2);
    }
    __syncthreads();
    __threadfence();                     // acquire: invalidate stale caches
}

// ================= single-launch mega kernel =================
// P1 layer1+tanh -> tg,sk | P2 layer2 k-split -> opart |
// P3 v+J (sums opart inline) -> jpart | P4 reduce+norms+mask -> out
__global__ __launch_bounds__(256, 2) void mega(
    const float* __restrict__ x,
    const float* __restrict__ Wf1, const float* __restrict__ bf1,
    const float* __restrict__ Wg1, const float* __restrict__ bg1,
    const float* __restrict__ Wk1, const float* __restrict__ bk1,
    const float* __restrict__ Wf2, const float* __restrict__ bf2,
    const float* __restrict__ Wg2, const float* __restrict__ bg2,
    const float* __restrict__ Wk2, const float* __restrict__ bk2,
    float* __restrict__ ws, float* __restrict__ out)
{
    const int bid = blockIdx.x;
    const int t   = threadIdx.x;

    float* skw   = ws + WS_SK;
    int*   bar   = (int*)(ws + WS_BAR);
    float* opart = ws + WS_OPART;
    float* jpart = ws + WS_JPART;
    float* tg    = ws + WS_JPART;        // alias: dead before P3 writes jpart

    __shared__ __align__(16) float smem[8192];   // 32 KB, reused per phase
    __shared__ float red[12];
    float4* sm4 = (float4*)smem;

    // ---------------- P1: layer 1 (tanh(x@W1^T+b1)) ----------------
    // unit = (m, ht 32-h slice, rt 8-row tile) : 3*32*16 = 1536 units
    for (int u = bid; u < 1536; u += GRID_) {
        const int m  = u >> 9;           // /512
        const int r9 = u & 511;
        const int ht = r9 >> 4;          // 0..31
        const int rt = r9 & 15;          // 0..15
        const int h0 = ht * 32, r0 = rt * 8;

        const float* W1 = (m == 0) ? Wf1 : (m == 1) ? Wg1 : Wk1;
        const float* b1 = (m == 0) ? bf1 : (m == 1) ? bg1 : bk1;

        __syncthreads();                 // smem reuse across units
        // stage 32 rows x 1KB contiguous -> swizzled LDS, coalesced
        const float4* wg = (const float4*)(W1 + h0 * N_);
        #pragma unroll
        for (int v = 0; v < 8; ++v) {
            const int f4  = t + 256 * v;             // 0..2047
            const int row = f4 >> 6, c = f4 & 63;
            sm4[(row << 6) | (c & 48) | ((c & 15) ^ (row & 15))] = wg[f4];
        }
        __syncthreads();

        const int hl = t & 15;           // h within 16-group
        const int kq = (t >> 4) & 3;     // k-quarter (64 k)
        const int w2i = (t >> 6) & 1;    // h-group (wave-uniform)
        const int rh = t >> 7;           // row-half (wave-uniform)
        const int hloc = w2i * 16 + hl;
        const int h = h0 + hloc;

        float acc[4] = {0.f, 0.f, 0.f, 0.f};
        const float4* wrow = sm4 + (hloc << 6) + (kq << 4);
        const float4* xg   = (const float4*)(x + (r0 + rh * 4) * N_) + (kq << 4);
        #pragma unroll 4
        for (int c = 0; c < 16; ++c) {
            const float4 wv = wrow[c ^ hl];          // conflict-free
            #pragma unroll
            for (int j = 0; j < 4; ++j) {
                const float4 xv = xg[(j << 6) + c];  // <=4 lines/instr
                acc[j] += wv.x*xv.x + wv.y*xv.y + wv.z*xv.z + wv.w*xv.w;
            }
        }
        #pragma unroll
        for (int j = 0; j < 4; ++j) {    // reduce over kq (lane bits 4,5)
            acc[j] += __shfl_xor(acc[j], 16, 64);
            acc[j] += __shfl_xor(acc[j], 32, 64);
        }
        float av = acc[0];               // static-index select (rule #20)
        av = (kq == 1) ? acc[1] : av;
        av = (kq == 2) ? acc[2] : av;
        av = (kq == 3) ? acc[3] : av;
        const float v0 = tanhf(av + b1[h]);
        const int r = r0 + rh * 4 + kq;
        tg[(m * BS_ + r) * H_ + h] = v0;
        if (m == 2) skw[r * H_ + h] = 1.0f - v0 * v0;
    }
    grid_barrier(bar + 0);

    // ---------------- P2: layer 2 k-split -> opart ----------------
    // unit = (m, ks 64-k slice, ih i-half, rt 8-row tile) : 1536 units
    for (int u = bid; u < 1536; u += GRID_) {
        const int m  = u >> 9;
        const int ks = (u >> 5) & 15;
        const int ih = (u >> 4) & 1;
        const int rt = u & 15;
        const int k0 = ks * 64, i0 = ih * 128, r0 = rt * 8;

        const float* W2 = (m == 0) ? Wf2 : (m == 1) ? Wg2 : Wk2;
        const float* b2 = (m == 0) ? bf2 : (m == 1) ? bg2 : bk2;

        __syncthreads();
        // stage [128 i][64 k] = 32KB, 16 thr/row (256B segments), swizzled
        #pragma unroll
        for (int v = 0; v < 8; ++v) {
            const int idx = t + 256 * v;             // 0..2047
            const int row = idx >> 4, c = idx & 15;
            sm4[(row << 4) | (c ^ (row & 15))] =
                ((const float4*)(W2 + (i0 + row) * H_ + k0))[c];
        }
        __syncthreads();

        const int i  = t & 127;
        const int rh = t >> 7;           // wave-uniform
        float acc[4] = {0.f, 0.f, 0.f, 0.f};
        const float4* wrow = sm4 + (i << 4);
        const float4* trow = (const float4*)(tg + (m * BS_ + r0 + rh * 4) * H_ + k0);
        #pragma unroll 4
        for (int c = 0; c < 16; ++c) {
            const float4 wv = wrow[c ^ (i & 15)];    // conflict-free
            #pragma unroll
            for (int j = 0; j < 4; ++j) {
                const float4 tv = trow[(j << 8) + c];  // wave-uniform, 1 line
                acc[j] += wv.x*tv.x + wv.y*tv.y + wv.z*tv.z + wv.w*tv.w;
            }
        }
        const float bv = (ks == 0) ? b2[i0 + i] : 0.0f;
        #pragma unroll
        for (int j = 0; j < 4; ++j)
            opart[((ks * 3 + m) * BS_ + r0 + rh * 4 + j) * N_ + i0 + i] = acc[j] + bv;
    }
    grid_barrier(bar + 1);

    // ---------------- P3: v+J partials (k3 body; sums opart inline) ----------
    {
        const int q  = bid & 15;         // h-slice
        const int rp = bid >> 4;         // 0..31 row tile
        const int r0 = rp * 4, h0 = q * 64;

        float (*fos)[256] = (float(*)[256])smem;           // 4 KB
        float (*gos)[256] = (float(*)[256])(smem + 1024);  // 4 KB
        float (*sfv)[64]  = (float(*)[64])(smem + 2048);   // 1 KB
        float (*sgv)[64]  = (float(*)[64])(smem + 2304);   // 1 KB

        // stage reduced fo/go rows straight from opart (replaces k25)
        for (int u2 = t; u2 < 1024; u2 += 256) {
            const int r = u2 >> 8, i = u2 & 255;
            float sf = 0.f, sg = 0.f;
            #pragma unroll
            for (int ks2 = 0; ks2 < 16; ++ks2) {
                sf += opart[((ks2 * 3 + 0) * BS_ + r0 + r) * N_ + i];
                sg += opart[((ks2 * 3 + 1) * BS_ + r0 + r) * N_ + i];
            }
            fos[r][i] = sf; gos[r][i] = sg;
        }
        __syncthreads();

        // phase A: v[r][h] = sum_i o[r][i]*Wk2[i][h]
        {
            const int hl = t & 63;
            const int rl = t >> 6;       // wave-uniform
            const int h  = h0 + hl;
            const float* w2 = Wk2 + h;
            float vf = 0.f, vg = 0.f;
            #pragma unroll 8
            for (int c = 0; c < 64; ++c) {
                const float4 of = ((const float4*)fos[rl])[c];
                const float4 og = ((const float4*)gos[rl])[c];
                const float w0  = w2[(4 * c + 0) * H_];
                const float w1v = w2[(4 * c + 1) * H_];
                const float w2v = w2[(4 * c + 2) * H_];
                const float w3  = w2[(4 * c + 3) * H_];
                vf += of.x * w0 + of.y * w1v + of.z * w2v + of.w * w3;
                vg += og.x * w0 + og.y * w1v + og.z * w2v + og.w * w3;
            }
            const float s = skw[(r0 + rl) * H_ + h];
            sfv[rl][hl] = s * vf;
            sgv[rl][hl] = s * vg;
        }
        __syncthreads();

        // phase B: J[r][j] = sum_hh sfv[r][hh]*Wk1[h0+hh][j]
        {
            float jf[4] = {0.f, 0.f, 0.f, 0.f};
            float jg[4] = {0.f, 0.f, 0.f, 0.f};
            const float* w1 = Wk1 + h0 * N_ + t;     // coalesced over t
            #pragma unroll 4
            for (int c = 0; c < 16; ++c) {
                const float w0  = w1[(4 * c + 0) * N_];
                const float wv1 = w1[(4 * c + 1) * N_];
                const float wv2 = w1[(4 * c + 2) * N_];
                const float wv3 = w1[(4 * c + 3) * N_];
                #pragma unroll
                for (int r = 0; r < 4; ++r) {
                    const float4 sf = ((const float4*)sfv[r])[c];
                    const float4 sg = ((const float4*)sgv[r])[c];
                    jf[r] += sf.x * w0 + sf.y * wv1 + sf.z * wv2 + sf.w * wv3;
                    jg[r] += sg.x * w0 + sg.y * wv1 + sg.z * wv2 + sg.w * wv3;
                }
            }
            #pragma unroll
            for (int r = 0; r < 4; ++r) {
                jpart[((q * 2 + 0) * BS_ + r0 + r) * N_ + t] = jf[r];
                jpart[((q * 2 + 1) * BS_ + r0 + r) * N_ + t] = jg[r];
            }
        }
    }
    grid_barrier(bar + 2);

    // ---------------- P4: final reduce + norms + mask -> out ----------------
    if (bid < BS_) {
        const int r = bid;
        float fo = 0.f, go = 0.f, ko = 0.f;
        #pragma unroll
        for (int ks2 = 0; ks2 < 16; ++ks2) {
            fo += opart[((ks2 * 3 + 0) * BS_ + r) * N_ + t];
            go += opart[((ks2 * 3 + 1) * BS_ + r) * N_ + t];
            ko += opart[((ks2 * 3 + 2) * BS_ + r) * N_ + t];
        }
        float jf = 0.f, jg = 0.f;
        #pragma unroll
        for (int q2 = 0; q2 < 16; ++q2) {
            jf += jpart[((q2 * 2 + 0) * BS_ + r) * N_ + t];
            jg += jpart[((q2 * 2 + 1) * BS_ + r) * N_ + t];
        }

        float v0 = ko * ko, v1 = jf * jf, v2 = ko * jg;
        #pragma unroll
        for (int o = 32; o > 0; o >>= 1) {
            v0 += __shfl_xor(v0, o, 64);
            v1 += __shfl_xor(v1, o, 64);
            v2 += __shfl_xor(v2, o, 64);
        }
        const int wid = t >> 6;
        if ((t & 63) == 0) {
            red[wid * 3 + 0] = v0;
            red[wid * 3 + 1] = v1;
            red[wid * 3 + 2] = v2;
        }
        __syncthreads();
        const float kn2 = red[0] + red[3] + red[6] + red[9];
        const float jf2 = red[1] + red[4] + red[7] + red[10];
        const float kjg = red[2] + red[5] + red[8] + red[11];

        const float knorm = sqrtf(kn2);
        const float kn4 = kn2 * kn2;
        const float kn8 = kn4 * kn4;
        const float c1 = sqrtf(jf2) - 60.0f * kn8 * knorm;
        const float c2 = kjg - 20.0f * kn8 * kn2;
        const float scale = ((c1 > 1e-8f) || (c2 < -1e-8f)) ? 0.5f : 1.0f;

        out[r * N_ + t] = (fo + go) * scale;
    }
}

// ================= fallback: round-2 proven fused kernel =================
__global__ __launch_bounds__(256) void manifold_fused(
    const float* __restrict__ x,
    const float* __restrict__ Wf1, const float* __restrict__ bf1v,
    const float* __restrict__ Wf2, const float* __restrict__ bf2v,
    const float* __restrict__ Wg1, const float* __restrict__ bg1v,
    const float* __restrict__ Wg2, const float* __restrict__ bg2v,
    const float* __restrict__ Wk1, const float* __restrict__ bk1v,
    const float* __restrict__ Wk2, const float* __restrict__ bk2v,
    float* __restrict__ out)
{
    const int b = blockIdx.x;
    const int t = threadIdx.x;
    __shared__ float xs[N_];
    __shared__ float tf[H_], tg[H_], tk[H_], sk[H_];
    __shared__ float fo[N_], go[N_];
    __shared__ float sfv[H_], sgv[H_];
    __shared__ float red[12];

    xs[t] = x[b * N_ + t];
    __syncthreads();
    {
        float acc[12];
        const float4* rows[12];
        #pragma unroll
        for (int m = 0; m < 4; ++m) {
            const int h = t + m * 256;
            rows[m]     = (const float4*)(Wf1 + h * N_);
            rows[4 + m] = (const float4*)(Wg1 + h * N_);
            rows[8 + m] = (const float4*)(Wk1 + h * N_);
            acc[m] = bf1v[h]; acc[4 + m] = bg1v[h]; acc[8 + m] = bk1v[h];
        }
        const float4* xs4 = (const float4*)xs;
        #pragma unroll 2
        for (int c = 0; c < 64; ++c) {
            float4 a = xs4[c];
            #pragma unroll
            for (int r = 0; r < 12; ++r) {
                float4 w = rows[r][c];
                acc[r] += w.x * a.x + w.y * a.y + w.z * a.z + w.w * a.w;
            }
        }
        #pragma unroll
        for (int m = 0; m < 4; ++m) {
            const int h = t + m * 256;
            float vtf = tanhf(acc[m]);
            float vtg = tanhf(acc[4 + m]);
            float vtk = tanhf(acc[8 + m]);
            tf[h] = vtf; tg[h] = vtg; tk[h] = vtk; sk[h] = 1.0f - vtk * vtk;
        }
    }
    __syncthreads();
    float af = bf2v[t], ag = bg2v[t], ak = bk2v[t];
    {
        const float4* rf = (const float4*)(Wf2 + t * H_);
        const float4* rg = (const float4*)(Wg2 + t * H_);
        const float4* rk = (const float4*)(Wk2 + t * H_);
        #pragma unroll 2
        for (int c = 0; c < 256; ++c) {
            float4 wf = rf[c], wg = rg[c], wk = rk[c];
            float4 vf = ((const float4*)tf)[c];
            af += wf.x*vf.x + wf.y*vf.y + wf.z*vf.z + wf.w*vf.w;
            float4 vg = ((const float4*)tg)[c];
            ag += wg.x*vg.x + wg.y*vg.y + wg.z*vg.z + wg.w*vg.w;
            float4 vk = ((const float4*)tk)[c];
            ak += wk.x*vk.x + wk.y*vk.y + wk.z*vk.z + wk.w*vk.w;
        }
    }
    fo[t] = af; go[t] = ag;
    __syncthreads();
    {
        float vf[4] = {0.f,0.f,0.f,0.f}, vg[4] = {0.f,0.f,0.f,0.f};
        const float* base = Wk2 + 4 * t;
        #pragma unroll 4
        for (int i = 0; i < N_; ++i) {
            float4 w = *(const float4*)(base + i * H_);
            float fv = fo[i], gv = go[i];
            vf[0]+=w.x*fv; vf[1]+=w.y*fv; vf[2]+=w.z*fv; vf[3]+=w.w*fv;
            vg[0]+=w.x*gv; vg[1]+=w.y*gv; vg[2]+=w.z*gv; vg[3]+=w.w*gv;
        }
        #pragma unroll
        for (int c = 0; c < 4; ++c) {
            sfv[4*t+c] = sk[4*t+c]*vf[c];
            sgv[4*t+c] = sk[4*t+c]*vg[c];
        }
    }
    __syncthreads();
    float jf = 0.f, jg = 0.f;
    {
        const float* col = Wk1 + t;
        #pragma unroll 4
        for (int c = 0; c < 256; ++c) {
            float4 s4 = ((const float4*)sfv)[c];
            float4 g4 = ((const float4*)sgv)[c];
            const int h = c * 4;
            float w0 = col[(h+0)*N_], w1 = col[(h+1)*N_];
            float w2 = col[(h+2)*N_], w3 = col[(h+3)*N_];
            jf += s4.x*w0 + s4.y*w1 + s4.z*w2 + s4.w*w3;
            jg += g4.x*w0 + g4.y*w1 + g4.z*w2 + g4.w*w3;
        }
    }
    float v0 = ak*ak, v1 = jf*jf, v2 = ak*jg;
    #pragma unroll
    for (int o = 32; o > 0; o >>= 1) {
        v0 += __shfl_xor(v0, o, 64);
        v1 += __shfl_xor(v1, o, 64);
        v2 += __shfl_xor(v2, o, 64);
    }
    const int wid = t >> 6;
    if ((t & 63) == 0) {
        red[wid*3+0] = v0; red[wid*3+1] = v1; red[wid*3+2] = v2;
    }
    __syncthreads();
    const float kn2 = red[0]+red[3]+red[6]+red[9];
    const float jf2 = red[1]+red[4]+red[7]+red[10];
    const float kjg = red[2]+red[5]+red[8]+red[11];
    const float knorm = sqrtf(kn2);
    const float kn4 = kn2*kn2, kn8 = kn4*kn4;
    const float c1 = sqrtf(jf2) - 60.0f*kn8*knorm;
    const float c2 = kjg - 20.0f*kn8*kn2;
    const float scale = ((c1 > 1e-8f) || (c2 < -1e-8f)) ? 0.5f : 1.0f;
    out[b*N_+t] = (af+ag)*scale;
}

extern "C" void kernel_launch(void* const* d_in, const int* in_sizes, int n_in,
                              void* d_out, int out_size, void* d_ws, size_t ws_size,
                              hipStream_t stream) {
    const float* x    = (const float*)d_in[1];
    const float* Wf1  = (const float*)d_in[2];
    const float* bf1v = (const float*)d_in[3];
    const float* Wf2  = (const float*)d_in[4];
    const float* bf2v = (const float*)d_in[5];
    const float* Wg1  = (const float*)d_in[6];
    const float* bg1v = (const float*)d_in[7];
    const float* Wg2  = (const float*)d_in[8];
    const float* bg2v = (const float*)d_in[9];
    const float* Wk1  = (const float*)d_in[10];
    const float* bk1v = (const float*)d_in[11];
    const float* Wk2  = (const float*)d_in[12];
    const float* bk2v = (const float*)d_in[13];
    float* out = (float*)d_out;

    if (ws_size < (size_t)WS_FLOATS * sizeof(float)) {
        manifold_fused<<<BS_, 256, 0, stream>>>(
            x, Wf1, bf1v, Wf2, bf2v, Wg1, bg1v, Wg2, bg2v,
            Wk1, bk1v, Wk2, bk2v, out);
        return;
    }

    float* ws = (float*)d_ws;
    // zero the 3 grid-barrier counters (workspace is poisoned every iter)
    hipMemsetAsync(ws + WS_BAR, 0, 64, stream);
    mega<<<GRID_, 256, 0, stream>>>(
        x, Wf1, bf1v, Wg1, bg1v, Wk1, bk1v,
        Wf2, bf2v, Wg2, bg2v, Wk2, bk2v,
        ws, out);
}

// Round 4
// 121.196 us; speedup vs baseline: 2.9018x; 2.9018x over previous
//
#include <hip/hip_runtime.h>
#include <stdint.h>

#define N_ 256
#define H_ 1024
#define BS_ 128

// ---------------- workspace layout (floats), all plain stores ----------------
// sk   : [128][1024]        @ 0          1 - tk^2
// oacc : [3][128][256]      @ 131072     reduced fo/go/ko
// opart: [32][3][128][256]  @ 229376     layer2 k-split partials (32 slices)
// jpart: [16][2][128][256]  @ 3375104    J h-split partials
#define WS_SK    0
#define WS_OACC  131072
#define WS_OPART 229376
#define WS_JPART 3375104
#define WS_FLOATS 4423680   // ~17.7 MB (harness ws is ~256 MB)

// ---- K12S: fused layer1+layer2-partial with LDS-STAGED weights. ----
// grid = 768 = 96 groups (m, ht 32-h slice) x 8 row-tiles (16 rows); 256 thr.
// 50 KB LDS -> exactly 3 blocks/CU, 12 waves/CU.
// All weight reads are coalesced global -> swizzled LDS; the per-lane-row
// (64-lines-per-instruction) TA-divergent reads of R0's k12 are gone.
// XCD swizzle: sid=(bx&7)*96+(bx>>3): each XCD owns 12 (m,ht) groups, all rt.
__global__ __launch_bounds__(256) void k12s(
    const float* __restrict__ x,
    const float* __restrict__ Wf1, const float* __restrict__ bf1,
    const float* __restrict__ Wg1, const float* __restrict__ bg1,
    const float* __restrict__ Wk1, const float* __restrict__ bk1,
    const float* __restrict__ Wf2, const float* __restrict__ bf2,
    const float* __restrict__ Wg2, const float* __restrict__ bg2,
    const float* __restrict__ Wk2, const float* __restrict__ bk2,
    float* __restrict__ sk, float* __restrict__ opart)
{
    const int bx  = blockIdx.x;
    const int sid = (bx & 7) * 96 + (bx >> 3);   // bijective XCD swizzle
    const int g   = sid >> 3;          // 0..95 weight group (m, ht)
    const int rt  = sid & 7;           // 0..7 row tile (16 rows)
    const int m   = g >> 5;            // 0..2
    const int ht  = g & 31;            // 0..31 h-slice of 32
    const int t   = threadIdx.x;
    const int h0  = ht * 32;
    const int r0  = rt * 16;

    const float* W1 = (m == 0) ? Wf1 : (m == 1) ? Wg1 : Wk1;
    const float* b1 = (m == 0) ? bf1 : (m == 1) ? bg1 : bk1;
    const float* W2 = (m == 0) ? Wf2 : (m == 1) ? Wg2 : Wk2;
    const float* b2 = (m == 0) ? bf2 : (m == 1) ? bg2 : bk2;

    __shared__ float4 wbuf[2048];                   // 32 KB, W1 then W2
    __shared__ __align__(16) float xs[16][256];     // 16 KB
    __shared__ __align__(16) float ts[16][32];      //  2 KB tanh acts

    // stage x rows r0..r0+15 (16 KB contiguous) + W1 rows h0..h0+31 (32 KB
    // contiguous), both flat coalesced. W1 swizzled: chunk low4 ^= row&15.
    {
        const float4* xsrc = (const float4*)(x + r0 * N_);
        #pragma unroll
        for (int v = 0; v < 4; ++v)
            ((float4*)xs)[t + 256 * v] = xsrc[t + 256 * v];
        const float4* wg = (const float4*)(W1 + h0 * N_);
        #pragma unroll
        for (int v = 0; v < 8; ++v) {
            const int f4  = t + 256 * v;            // 0..2047
            const int row = f4 >> 6, c = f4 & 63;
            wbuf[(row << 6) | (c & 48) | ((c & 15) ^ (row & 15))] = wg[f4];
        }
    }
    __syncthreads();

    // ---- phase 1: thread = (hl=t&15, kq=(t>>4)&3 k-quarter,
    //               hgrp=(t>>6)&1, rh=t>>7 row-half) — hgrp/rh wave-uniform.
    {
        const int hl   = t & 15;
        const int kq   = (t >> 4) & 3;
        const int hgrp = (t >> 6) & 1;
        const int rh   = t >> 7;
        const int hloc = hgrp * 16 + hl;
        const int h    = h0 + hloc;

        float acc[8] = {0.f,0.f,0.f,0.f,0.f,0.f,0.f,0.f};
        const float4* wrow = wbuf + (hloc << 6) + (kq << 4);
        #pragma unroll
        for (int cl = 0; cl < 16; ++cl) {
            const float4 wv = wrow[cl ^ hl];        // de-swizzle, spread banks
            #pragma unroll
            for (int r = 0; r < 8; ++r) {
                const float4 xv = ((const float4*)xs[rh * 8 + r])[(kq << 4) + cl];
                acc[r] += wv.x*xv.x + wv.y*xv.y + wv.z*xv.z + wv.w*xv.w;
            }
        }
        #pragma unroll
        for (int r = 0; r < 8; ++r) {               // reduce over kq (bits 4,5)
            acc[r] += __shfl_xor(acc[r], 16, 64);
            acc[r] += __shfl_xor(acc[r], 32, 64);
        }
        // kq lane j finalizes rows rh*8 + 2j, 2j+1 (static-index selects)
        float va = acc[0], vb = acc[1];
        va = (kq == 1) ? acc[2] : va;  vb = (kq == 1) ? acc[3] : vb;
        va = (kq == 2) ? acc[4] : va;  vb = (kq == 2) ? acc[5] : vb;
        va = (kq == 3) ? acc[6] : va;  vb = (kq == 3) ? acc[7] : vb;
        const float bv = b1[h];
        const float v0 = tanhf(va + bv), v1 = tanhf(vb + bv);
        const int rl = rh * 8 + kq * 2;
        ts[rl][hloc]     = v0;
        ts[rl + 1][hloc] = v1;
        if (m == 2) {
            sk[(r0 + rl) * H_ + h]     = 1.0f - v0 * v0;
            sk[(r0 + rl + 1) * H_ + h] = 1.0f - v1 * v1;
        }
    }
    __syncthreads();

    // re-stage wbuf with W2 slice [256 i][32 h] = 32 KB.
    // 8 threads per row read 128B contiguous segments (fully-used lines).
    {
        #pragma unroll
        for (int v = 0; v < 8; ++v) {
            const int idx = t + 256 * v;            // 0..2047
            const int row = idx >> 3, c = idx & 7;
            wbuf[(row << 3) | (c ^ (row & 7))] =
                ((const float4*)(W2 + row * H_ + h0))[c];
        }
    }
    __syncthreads();

    // ---- phase 2: thread = output channel i = t; 16 rows ----
    {
        float acc[16];
        const float bv2 = (ht == 0) ? b2[t] : 0.0f;
        #pragma unroll
        for (int r = 0; r < 16; ++r) acc[r] = bv2;

        const float4* wrow = wbuf + (t << 3);
        #pragma unroll
        for (int c = 0; c < 8; ++c) {
            const float4 wv = wrow[c ^ (t & 7)];    // de-swizzle
            #pragma unroll
            for (int r = 0; r < 16; ++r) {
                const float4 av = ((const float4*)ts[r])[c];  // broadcast
                acc[r] += wv.x*av.x + wv.y*av.y + wv.z*av.z + wv.w*av.w;
            }
        }
        #pragma unroll
        for (int r = 0; r < 16; ++r)
            opart[((ht * 3 + m) * BS_ + r0 + r) * N_ + t] = acc[r];
    }
}

// ---- K25: reduce opart (32 slices) -> oacc. grid = 384 ----
__global__ __launch_bounds__(256) void k25_reduce(
    const float* __restrict__ opart, float* __restrict__ oacc)
{
    const int tid = blockIdx.x * 256 + threadIdx.x;   // 0..98303
    float s = 0.f;
    #pragma unroll
    for (int ks = 0; ks < 32; ++ks)
        s += opart[ks * (3 * BS_ * N_) + tid];
    oacc[tid] = s;
}

// ---- K3: fused v+J partials, reads reduced oacc. grid = 512 (R0-proven) ----
__global__ __launch_bounds__(256) void k3_vj(
    const float* __restrict__ Wk1, const float* __restrict__ Wk2,
    const float* __restrict__ oacc, const float* __restrict__ sk,
    float* __restrict__ jpart)
{
    const int q  = blockIdx.x & 15;    // 0..15 h-slice
    const int rp = blockIdx.x >> 4;    // 0..31 row tile
    const int t  = threadIdx.x;
    const int r0 = rp * 4;
    const int h0 = q * 64;

    __shared__ float fos[4][256], gos[4][256];   // 8 KB
    __shared__ float sfv[4][64], sgv[4][64];     // 2 KB

    for (int u = t; u < 1024; u += 256) {
        const int r = u >> 8, i = u & 255;
        fos[r][i] = oacc[(r0 + r) * N_ + i];
        gos[r][i] = oacc[(BS_ + r0 + r) * N_ + i];
    }
    __syncthreads();

    {
        const int hl = t & 63;
        const int rl = t >> 6;         // 0..3, wave-uniform
        const int h  = h0 + hl;
        const float* w2 = Wk2 + h;
        float vf = 0.f, vg = 0.f;
        #pragma unroll 8
        for (int c = 0; c < 64; ++c) {
            const float4 of = ((const float4*)fos[rl])[c];
            const float4 og = ((const float4*)gos[rl])[c];
            const float w0  = w2[(4 * c + 0) * H_];
            const float w1v = w2[(4 * c + 1) * H_];
            const float w2v = w2[(4 * c + 2) * H_];
            const float w3  = w2[(4 * c + 3) * H_];
            vf += of.x * w0 + of.y * w1v + of.z * w2v + of.w * w3;
            vg += og.x * w0 + og.y * w1v + og.z * w2v + og.w * w3;
        }
        const float s = sk[(r0 + rl) * H_ + h];
        sfv[rl][hl] = s * vf;
        sgv[rl][hl] = s * vg;
    }
    __syncthreads();

    {
        float jf[4] = {0.f, 0.f, 0.f, 0.f};
        float jg[4] = {0.f, 0.f, 0.f, 0.f};
        const float* w1 = Wk1 + h0 * N_ + t;    // coalesced over t
        #pragma unroll 4
        for (int c = 0; c < 16; ++c) {
            const float w0  = w1[(4 * c + 0) * N_];
            const float wv1 = w1[(4 * c + 1) * N_];
            const float wv2 = w1[(4 * c + 2) * N_];
            const float wv3 = w1[(4 * c + 3) * N_];
            #pragma unroll
            for (int r = 0; r < 4; ++r) {
                const float4 sf = ((const float4*)sfv[r])[c];
                const float4 sg = ((const float4*)sgv[r])[c];
                jf[r] += sf.x * w0 + sf.y * wv1 + sf.z * wv2 + sf.w * wv3;
                jg[r] += sg.x * w0 + sg.y * wv1 + sg.z * wv2 + sg.w * wv3;
            }
        }
        #pragma unroll
        for (int r = 0; r < 4; ++r) {
            jpart[((q * 2 + 0) * BS_ + r0 + r) * N_ + t] = jf[r];
            jpart[((q * 2 + 1) * BS_ + r0 + r) * N_ + t] = jg[r];
        }
    }
}

// ---- K4: reduce jpart + norms + mask + output. grid = 128 (R0-proven) ----
__global__ __launch_bounds__(256) void k4_final(
    const float* __restrict__ oacc,
    const float* __restrict__ jpart,
    float* __restrict__ out)
{
    const int r = blockIdx.x;
    const int t = threadIdx.x;
    __shared__ float red[12];

    const float fo = oacc[r * N_ + t];
    const float go = oacc[(BS_ + r) * N_ + t];
    const float ko = oacc[(2 * BS_ + r) * N_ + t];

    float jf = 0.f, jg = 0.f;
    #pragma unroll
    for (int q = 0; q < 16; ++q) {
        jf += jpart[((q * 2 + 0) * BS_ + r) * N_ + t];
        jg += jpart[((q * 2 + 1) * BS_ + r) * N_ + t];
    }

    float v0 = ko * ko, v1 = jf * jf, v2 = ko * jg;
    #pragma unroll
    for (int o = 32; o > 0; o >>= 1) {
        v0 += __shfl_xor(v0, o, 64);
        v1 += __shfl_xor(v1, o, 64);
        v2 += __shfl_xor(v2, o, 64);
    }
    const int wid = t >> 6;
    if ((t & 63) == 0) {
        red[wid * 3 + 0] = v0;
        red[wid * 3 + 1] = v1;
        red[wid * 3 + 2] = v2;
    }
    __syncthreads();
    const float kn2 = red[0] + red[3] + red[6] + red[9];
    const float jf2 = red[1] + red[4] + red[7] + red[10];
    const float kjg = red[2] + red[5] + red[8] + red[11];

    const float knorm = sqrtf(kn2);
    const float kn4 = kn2 * kn2;
    const float kn8 = kn4 * kn4;
    const float c1 = sqrtf(jf2) - 60.0f * kn8 * knorm;
    const float c2 = kjg - 20.0f * kn8 * kn2;
    const float scale = ((c1 > 1e-8f) || (c2 < -1e-8f)) ? 0.5f : 1.0f;

    out[r * N_ + t] = (fo + go) * scale;
}

// ================= fallback: round-2 proven fused kernel =================
__global__ __launch_bounds__(256) void manifold_fused(
    const float* __restrict__ x,
    const float* __restrict__ Wf1, const float* __restrict__ bf1v,
    const float* __restrict__ Wf2, const float* __restrict__ bf2v,
    const float* __restrict__ Wg1, const float* __restrict__ bg1v,
    const float* __restrict__ Wg2, const float* __restrict__ bg2v,
    const float* __restrict__ Wk1, const float* __restrict__ bk1v,
    const float* __restrict__ Wk2, const float* __restrict__ bk2v,
    float* __restrict__ out)
{
    const int b = blockIdx.x;
    const int t = threadIdx.x;
    __shared__ float xs[N_];
    __shared__ float tf[H_], tg[H_], tk[H_], sk[H_];
    __shared__ float fo[N_], go[N_];
    __shared__ float sfv[H_], sgv[H_];
    __shared__ float red[12];

    xs[t] = x[b * N_ + t];
    __syncthreads();
    {
        float acc[12];
        const float4* rows[12];
        #pragma unroll
        for (int m = 0; m < 4; ++m) {
            const int h = t + m * 256;
            rows[m]     = (const float4*)(Wf1 + h * N_);
            rows[4 + m] = (const float4*)(Wg1 + h * N_);
            rows[8 + m] = (const float4*)(Wk1 + h * N_);
            acc[m] = bf1v[h]; acc[4 + m] = bg1v[h]; acc[8 + m] = bk1v[h];
        }
        const float4* xs4 = (const float4*)xs;
        #pragma unroll 2
        for (int c = 0; c < 64; ++c) {
            float4 a = xs4[c];
            #pragma unroll
            for (int r = 0; r < 12; ++r) {
                float4 w = rows[r][c];
                acc[r] += w.x * a.x + w.y * a.y + w.z * a.z + w.w * a.w;
            }
        }
        #pragma unroll
        for (int m = 0; m < 4; ++m) {
            const int h = t + m * 256;
            float vtf = tanhf(acc[m]);
            float vtg = tanhf(acc[4 + m]);
            float vtk = tanhf(acc[8 + m]);
            tf[h] = vtf; tg[h] = vtg; tk[h] = vtk; sk[h] = 1.0f - vtk * vtk;
        }
    }
    __syncthreads();
    float af = bf2v[t], ag = bg2v[t], ak = bk2v[t];
    {
        const float4* rf = (const float4*)(Wf2 + t * H_);
        const float4* rg = (const float4*)(Wg2 + t * H_);
        const float4* rk = (const float4*)(Wk2 + t * H_);
        #pragma unroll 2
        for (int c = 0; c < 256; ++c) {
            float4 wf = rf[c], wg = rg[c], wk = rk[c];
            float4 vf = ((const float4*)tf)[c];
            af += wf.x*vf.x + wf.y*vf.y + wf.z*vf.z + wf.w*vf.w;
            float4 vg = ((const float4*)tg)[c];
            ag += wg.x*vg.x + wg.y*vg.y + wg.z*vg.z + wg.w*vg.w;
            float4 vk = ((const float4*)tk)[c];
            ak += wk.x*vk.x + wk.y*vk.y + wk.z*vk.z + wk.w*vk.w;
        }
    }
    fo[t] = af; go[t] = ag;
    __syncthreads();
    {
        float vf[4] = {0.f,0.f,0.f,0.f}, vg[4] = {0.f,0.f,0.f,0.f};
        const float* base = Wk2 + 4 * t;
        #pragma unroll 4
        for (int i = 0; i < N_; ++i) {
            float4 w = *(const float4*)(base + i * H_);
            float fv = fo[i], gv = go[i];
            vf[0]+=w.x*fv; vf[1]+=w.y*fv; vf[2]+=w.z*fv; vf[3]+=w.w*fv;
            vg[0]+=w.x*gv; vg[1]+=w.y*gv; vg[2]+=w.z*gv; vg[3]+=w.w*gv;
        }
        #pragma unroll
        for (int c = 0; c < 4; ++c) {
            sfv[4*t+c] = sk[4*t+c]*vf[c];
            sgv[4*t+c] = sk[4*t+c]*vg[c];
        }
    }
    __syncthreads();
    float jf = 0.f, jg = 0.f;
    {
        const float* col = Wk1 + t;
        #pragma unroll 4
        for (int c = 0; c < 256; ++c) {
            float4 s4 = ((const float4*)sfv)[c];
            float4 g4 = ((const float4*)sgv)[c];
            const int h = c * 4;
            float w0 = col[(h+0)*N_], w1 = col[(h+1)*N_];
            float w2 = col[(h+2)*N_], w3 = col[(h+3)*N_];
            jf += s4.x*w0 + s4.y*w1 + s4.z*w2 + s4.w*w3;
            jg += g4.x*w0 + g4.y*w1 + g4.z*w2 + g4.w*w3;
        }
    }
    float v0 = ak*ak, v1 = jf*jf, v2 = ak*jg;
    #pragma unroll
    for (int o = 32; o > 0; o >>= 1) {
        v0 += __shfl_xor(v0, o, 64);
        v1 += __shfl_xor(v1, o, 64);
        v2 += __shfl_xor(v2, o, 64);
    }
    const int wid = t >> 6;
    if ((t & 63) == 0) {
        red[wid*3+0] = v0; red[wid*3+1] = v1; red[wid*3+2] = v2;
    }
    __syncthreads();
    const float kn2 = red[0]+red[3]+red[6]+red[9];
    const float jf2 = red[1]+red[4]+red[7]+red[10];
    const float kjg = red[2]+red[5]+red[8]+red[11];
    const float knorm = sqrtf(kn2);
    const float kn4 = kn2*kn2, kn8 = kn4*kn4;
    const float c1 = sqrtf(jf2) - 60.0f*kn8*knorm;
    const float c2 = kjg - 20.0f*kn8*kn2;
    const float scale = ((c1 > 1e-8f) || (c2 < -1e-8f)) ? 0.5f : 1.0f;
    out[b*N_+t] = (af+ag)*scale;
}

extern "C" void kernel_launch(void* const* d_in, const int* in_sizes, int n_in,
                              void* d_out, int out_size, void* d_ws, size_t ws_size,
                              hipStream_t stream) {
    const float* x    = (const float*)d_in[1];
    const float* Wf1  = (const float*)d_in[2];
    const float* bf1v = (const float*)d_in[3];
    const float* Wf2  = (const float*)d_in[4];
    const float* bf2v = (const float*)d_in[5];
    const float* Wg1  = (const float*)d_in[6];
    const float* bg1v = (const float*)d_in[7];
    const float* Wg2  = (const float*)d_in[8];
    const float* bg2v = (const float*)d_in[9];
    const float* Wk1  = (const float*)d_in[10];
    const float* bk1v = (const float*)d_in[11];
    const float* Wk2  = (const float*)d_in[12];
    const float* bk2v = (const float*)d_in[13];
    float* out = (float*)d_out;

    if (ws_size < (size_t)WS_FLOATS * sizeof(float)) {
        manifold_fused<<<BS_, 256, 0, stream>>>(
            x, Wf1, bf1v, Wf2, bf2v, Wg1, bg1v, Wg2, bg2v,
            Wk1, bk1v, Wk2, bk2v, out);
        return;
    }

    float* ws    = (float*)d_ws;
    float* sk    = ws + WS_SK;
    float* oacc  = ws + WS_OACC;
    float* opart = ws + WS_OPART;
    float* jpart = ws + WS_JPART;

    k12s      <<<768, 256, 0, stream>>>(x, Wf1, bf1v, Wg1, bg1v, Wk1, bk1v,
                                        Wf2, bf2v, Wg2, bg2v, Wk2, bk2v,
                                        sk, opart);
    k25_reduce<<<384, 256, 0, stream>>>(opart, oacc);
    k3_vj     <<<512, 256, 0, stream>>>(Wk1, Wk2, oacc, sk, jpart);
    k4_final  <<<BS_, 256, 0, stream>>>(oacc, jpart, out);
}